// Round 12
// baseline (54.166 us; speedup 1.0000x reference)
//
#include <hip/hip_runtime.h>
#include <math.h>

// diag-RTRL, round 12: r11 structure + INVERTED cache policy:
//   nt LOADS on E (don't allocate in L3) + PLAIN stores on out (allocate).
//   s      = tanh(0.9*u + x@W)         [32,1024]
//   u_new  = 0.9*u + x@W               [32,1024]
//   E_new  = 0.9*E + x[:,:,None]       [32,1024,1024]  (268 MB stream, dominates)
//
// Model (r11 counters): footprint E134+out134+W4 = 272MB > 256MB L3, so L3
// keeps only half of E (FETCH 68MB) and out streams to HBM (WRITE 131MB) ->
// 200MB HBM-side mixed R/W. HBM raw BW is NOT binding (4.2 < 6.29 TB/s);
// the binding term is the mixed-R/W copy ceiling (6.29 vs 6.88 write-only).
// Flip: nt-load E (L3 stops caching the read stream) -> L3 retains the whole
// out buffer -> replays rewrite dirty L3 lines in place -> HBM becomes a
// ~134MB pure-read stream, no turnaround.
// If honored: FETCH->~134MB, WRITE-><20MB, dur ~35-40us.
// If ignored: unchanged -> declare roofline (89% of copy ceiling).

#define BETA 0.9f

constexpr int Bb   = 32;
constexpr int D_IN = 1024;
constexpr int D_H  = 1024;

constexpr int THREADS     = 256;
constexpr int GEMM_BLOCKS = 1024;   // (b, j-tile32): 32 x 32
constexpr int GRID        = 2048;
constexpr int TRIPS_G     = 14;     // E trips for GEMM blocks (+ ~1.5 trips GEMM)
constexpr int TRIPS_E     = 18;     // E trips for plain blocks
// 1024*14 + 1024*18 = 32768 trips * 256 f4 = 8,388,608 f4 = full E.

typedef float f4 __attribute__((ext_vector_type(4)));

__global__ __launch_bounds__(THREADS) void rtrl_one(
    const float* __restrict__ x,   // [32,1024]
    const float* __restrict__ W,   // [1024,1024]
    const float* __restrict__ u,   // [32,1024]
    const float* __restrict__ E,   // [32,1024,1024]
    float* __restrict__ out)       // [s | u_new | E_new]
{
    __shared__ float xs[D_IN];     // 4 KB : this block's x row
    __shared__ float part[8][32];  // 1 KB : k-split partials

    const int blk = blockIdx.x;
    const int tid = threadIdx.x;

    if (blk < GEMM_BLOCKS) {
        // ---------- GEMM: b = blk>>5, j-tile = (blk&31)*32, 8-way k-split ----
        const int b  = blk >> 5;
        const int j0 = (blk & 31) * 32;
        const int jc = tid & 31;          // column within tile
        const int ks = tid >> 5;          // k-segment 0..7 (128 rows each)

        // stage x row (4 KB), f4-vectorized cooperative load
        {
            f4* xs4 = (f4*)xs;
            const f4* x4 = (const f4*)(x + b * D_IN);
            xs4[tid] = x4[tid];           // 256 f4 = 1024 floats
        }
        __syncthreads();

        // 128 FMAs: W direct (32 lanes consecutive j -> 128B segments;
        // W[:,jtile] reused by 32 b-blocks via L2/L3). 4 indep accumulators.
        const float* __restrict__ Wp = W + (ks * 128) * D_H + j0 + jc;
        const float* __restrict__ xp = xs + ks * 128;
        float a0 = 0.f, a1 = 0.f, a2 = 0.f, a3 = 0.f;
        #pragma unroll 8
        for (int i = 0; i < 128; i += 4) {
            a0 = fmaf(xp[i + 0], Wp[(i + 0) * D_H], a0);
            a1 = fmaf(xp[i + 1], Wp[(i + 1) * D_H], a1);
            a2 = fmaf(xp[i + 2], Wp[(i + 2) * D_H], a2);
            a3 = fmaf(xp[i + 3], Wp[(i + 3) * D_H], a3);
        }
        part[ks][jc] = (a0 + a1) + (a2 + a3);
        __syncthreads();

        // fixed-order 8-way reduce + epilogue by first 32 threads
        if (tid < 32) {
            float acc = part[0][tid];
            #pragma unroll
            for (int k = 1; k < 8; ++k) acc += part[k][tid];
            const int   idx = b * D_H + j0 + tid;
            const float un  = BETA * u[idx] + acc;
            out[idx]            = tanhf(un);   // s
            out[Bb * D_H + idx] = un;          // u_new
        }
    }

    // ---------- E stream: nt loads (no L3 alloc), plain stores (L3 alloc) ----
    const f4* __restrict__ E4 = (const f4*)E;
    f4* __restrict__ O4 = (f4*)(out + 2 * Bb * D_H);

    const int ntrips = (blk < GEMM_BLOCKS) ? TRIPS_G : TRIPS_E;
    // xi = global trip index base: pure SGPR arithmetic, block-uniform.
    const int xi     = (blk < GEMM_BLOCKS)
                     ? blk * TRIPS_G
                     : GEMM_BLOCKS * TRIPS_G + (blk - GEMM_BLOCKS) * TRIPS_E;

    int v = xi * THREADS + tid;
    int t = 0;
    for (; t + 8 <= ntrips; t += 8) {     // 8 loads in flight
        f4 e[8];
        #pragma unroll
        for (int j = 0; j < 8; ++j) e[j] = __builtin_nontemporal_load(&E4[v + j * 256]);
        float xv[8];
        #pragma unroll
        for (int j = 0; j < 8; ++j) xv[j] = x[xi + t + j];   // SGPR index -> s_load
        #pragma unroll
        for (int j = 0; j < 8; ++j)
            O4[v + j * 256] = e[j] * BETA + xv[j];           // plain store: L3-alloc
        v += 8 * 256;
    }
    for (; t + 4 <= ntrips; t += 4) {
        f4 e[4];
        #pragma unroll
        for (int j = 0; j < 4; ++j) e[j] = __builtin_nontemporal_load(&E4[v + j * 256]);
        float xv[4];
        #pragma unroll
        for (int j = 0; j < 4; ++j) xv[j] = x[xi + t + j];
        #pragma unroll
        for (int j = 0; j < 4; ++j)
            O4[v + j * 256] = e[j] * BETA + xv[j];
        v += 4 * 256;
    }
    for (; t < ntrips; ++t) {
        f4 e = __builtin_nontemporal_load(&E4[v]);
        const float xv = x[xi + t];
        O4[v] = e * BETA + xv;
        v += 256;
    }
}

extern "C" void kernel_launch(void* const* d_in, const int* in_sizes, int n_in,
                              void* d_out, int out_size, void* d_ws, size_t ws_size,
                              hipStream_t stream) {
    const float* x = (const float*)d_in[0];
    const float* W = (const float*)d_in[1];
    const float* u = (const float*)d_in[2];
    const float* E = (const float*)d_in[3];
    float* out = (float*)d_out;

    rtrl_one<<<GRID, THREADS, 0, stream>>>(x, W, u, E, out);
}

// Round 13
// 47.810 us; speedup vs baseline: 1.1329x; 1.1329x over previous
//
#include <hip/hip_runtime.h>
#include <math.h>

// diag-RTRL, round 13: REVERT to round-11 (empirical best, 47.76us).
//   s      = tanh(0.9*u + x@W)         [32,1024]
//   u_new  = 0.9*u + x@W               [32,1024]
//   E_new  = 0.9*E + x[:,:,None]       [32,1024,1024]  (268 MB stream, dominates)
//
// Final configuration after 12 rounds of lever testing:
//  * single kernel, 2048 blocks: 1024 GEMM blocks (one (b, 32-col j-tile)
//    each, K=1024 split 8-way across the block's own threads, LDS reduce,
//    direct s/u_new write) + 1024 pure-stream blocks. 14/18 trip balance.
//  * E stream: f4 loads (plain), NT stores, ILP-8, SGPR-uniform x loads.
//  * Dead levers (measured): store cache hints (none/nt/sc1: no FETCH delta;
//    sc1 corrupts read-back), nt loads (54.2us, -13%), cross-block fusion
//    (fences 83us / coop-launch broken / split-K two-kernel 48.6us),
//    narrow GEMM (<=128 blocks: latency tail, 64-90us).
// At 47.76us: 268 MB logical / 6.29 TB/s copy ceiling = 89% -> roofline
// for this traffic pattern; declare <<ROOFLINE>> on reproduction.

#define BETA 0.9f

constexpr int Bb   = 32;
constexpr int D_IN = 1024;
constexpr int D_H  = 1024;

constexpr int THREADS     = 256;
constexpr int GEMM_BLOCKS = 1024;   // (b, j-tile32): 32 x 32
constexpr int GRID        = 2048;
constexpr int TRIPS_G     = 14;     // E trips for GEMM blocks (+ ~1.5 trips GEMM)
constexpr int TRIPS_E     = 18;     // E trips for plain blocks
// 1024*14 + 1024*18 = 32768 trips * 256 f4 = 8,388,608 f4 = full E.

typedef float f4 __attribute__((ext_vector_type(4)));

__global__ __launch_bounds__(THREADS) void rtrl_one(
    const float* __restrict__ x,   // [32,1024]
    const float* __restrict__ W,   // [1024,1024]
    const float* __restrict__ u,   // [32,1024]
    const float* __restrict__ E,   // [32,1024,1024]
    float* __restrict__ out)       // [s | u_new | E_new]
{
    __shared__ float xs[D_IN];     // 4 KB : this block's x row
    __shared__ float part[8][32];  // 1 KB : k-split partials

    const int blk = blockIdx.x;
    const int tid = threadIdx.x;

    if (blk < GEMM_BLOCKS) {
        // ---------- GEMM: b = blk>>5, j-tile = (blk&31)*32, 8-way k-split ----
        const int b  = blk >> 5;
        const int j0 = (blk & 31) * 32;
        const int jc = tid & 31;          // column within tile
        const int ks = tid >> 5;          // k-segment 0..7 (128 rows each)

        // stage x row (4 KB), f4-vectorized cooperative load
        {
            f4* xs4 = (f4*)xs;
            const f4* x4 = (const f4*)(x + b * D_IN);
            xs4[tid] = x4[tid];           // 256 f4 = 1024 floats
        }
        __syncthreads();

        // 128 FMAs: W direct (32 lanes consecutive j -> 128B segments;
        // W[:,jtile] reused by 32 b-blocks via L2/L3). 4 indep accumulators.
        const float* __restrict__ Wp = W + (ks * 128) * D_H + j0 + jc;
        const float* __restrict__ xp = xs + ks * 128;
        float a0 = 0.f, a1 = 0.f, a2 = 0.f, a3 = 0.f;
        #pragma unroll 8
        for (int i = 0; i < 128; i += 4) {
            a0 = fmaf(xp[i + 0], Wp[(i + 0) * D_H], a0);
            a1 = fmaf(xp[i + 1], Wp[(i + 1) * D_H], a1);
            a2 = fmaf(xp[i + 2], Wp[(i + 2) * D_H], a2);
            a3 = fmaf(xp[i + 3], Wp[(i + 3) * D_H], a3);
        }
        part[ks][jc] = (a0 + a1) + (a2 + a3);
        __syncthreads();

        // fixed-order 8-way reduce + epilogue by first 32 threads
        if (tid < 32) {
            float acc = part[0][tid];
            #pragma unroll
            for (int k = 1; k < 8; ++k) acc += part[k][tid];
            const int   idx = b * D_H + j0 + tid;
            const float un  = BETA * u[idx] + acc;
            out[idx]            = tanhf(un);   // s
            out[Bb * D_H + idx] = un;          // u_new
        }
    }

    // ---------- E stream: contiguous region per block ----------
    const f4* __restrict__ E4 = (const f4*)E;
    f4* __restrict__ O4 = (f4*)(out + 2 * Bb * D_H);

    const int ntrips = (blk < GEMM_BLOCKS) ? TRIPS_G : TRIPS_E;
    // xi = global trip index base: pure SGPR arithmetic, block-uniform.
    const int xi     = (blk < GEMM_BLOCKS)
                     ? blk * TRIPS_G
                     : GEMM_BLOCKS * TRIPS_G + (blk - GEMM_BLOCKS) * TRIPS_E;

    int v = xi * THREADS + tid;
    int t = 0;
    for (; t + 8 <= ntrips; t += 8) {     // 8 loads in flight
        f4 e[8];
        #pragma unroll
        for (int j = 0; j < 8; ++j) e[j] = E4[v + j * 256];
        float xv[8];
        #pragma unroll
        for (int j = 0; j < 8; ++j) xv[j] = x[xi + t + j];   // SGPR index -> s_load
        #pragma unroll
        for (int j = 0; j < 8; ++j)
            __builtin_nontemporal_store(e[j] * BETA + xv[j], &O4[v + j * 256]);
        v += 8 * 256;
    }
    for (; t + 4 <= ntrips; t += 4) {
        f4 e[4];
        #pragma unroll
        for (int j = 0; j < 4; ++j) e[j] = E4[v + j * 256];
        float xv[4];
        #pragma unroll
        for (int j = 0; j < 4; ++j) xv[j] = x[xi + t + j];
        #pragma unroll
        for (int j = 0; j < 4; ++j)
            __builtin_nontemporal_store(e[j] * BETA + xv[j], &O4[v + j * 256]);
        v += 4 * 256;
    }
    for (; t < ntrips; ++t) {
        f4 e = E4[v];
        const float xv = x[xi + t];
        __builtin_nontemporal_store(e * BETA + xv, &O4[v]);
        v += 256;
    }
}

extern "C" void kernel_launch(void* const* d_in, const int* in_sizes, int n_in,
                              void* d_out, int out_size, void* d_ws, size_t ws_size,
                              hipStream_t stream) {
    const float* x = (const float*)d_in[0];
    const float* W = (const float*)d_in[1];
    const float* u = (const float*)d_in[2];
    const float* E = (const float*)d_in[3];
    float* out = (float*)d_out;

    rtrl_one<<<GRID, THREADS, 0, stream>>>(x, W, u, E, out);
}